// Round 4
// 671.389 us; speedup vs baseline: 1.0008x; 1.0008x over previous
//
#include <hip/hip_runtime.h>

// EdgeTransition fused pipeline, bf16-MFMA version.
//
// R4: byte-exact revert to the passing 671.9us kernel, with ONE change:
// buffer role swap in edge_mlp to drop the mid-phase barrier (5 -> 4).
//   hl: h (staged)  -> t2 (phase-2 output, read by phase 3)
//   tl: t1 (phase-1 output, read by phase 2) -> e fp32 overlay (LN input)
// The old layout kept t1/t2 both in tl, needing an extra __syncthreads()
// between phase-2 reads and the t2 overwrite. With the swap the existing
// S1/S2 barriers already order everything.
//
// d_ws layout:
//   [0)            nproj bf16 [N_NODES, 64]              12,800,000 B
//   [+12800000)    W1p  packed bf16 frags (12 nt,6 ks)       73,728 B
//   [+12873728)    W2p  packed                               73,728 B
//   [+12947456)    Wfp  packed (4 nt, 6 ks)                  24,576 B
//   [+12972032)    Wip  packed (4 nt, 4 ks)                  16,384 B
//
// Fragment conventions (mfma_f32_16x16x32_bf16, guide §3 m89/m120-verified):
//   A: lane holds A[m=lane&15][k=quad*8+j], j=0..7   (quad = lane>>4)
//   B: lane holds B[k=quad*8+j][n=lane&15]
//   C/D: col = lane&15, row = quad*4 + reg

typedef __bf16 bf16x8 __attribute__((ext_vector_type(8)));
typedef float  f32x4  __attribute__((ext_vector_type(4)));

#define LN_EPS 1e-5f

// ---------------- weight packing ----------------
__global__ __launch_bounds__(256) void pack_weights_kernel(
    const float* __restrict__ W, int KS, int NT, int N,
    __bf16* __restrict__ dst, int total)
{
    const int t = blockIdx.x * 256 + threadIdx.x;
    if (t >= total) return;
    const int lane = t & 63;
    const int ks   = (t >> 6) % KS;
    const int nt   = t / (KS * 64);
    const int n  = nt * 16 + (lane & 15);
    const int k0 = ks * 32 + (lane >> 4) * 8;
    bf16x8 v;
    #pragma unroll
    for (int j = 0; j < 8; ++j) v[j] = (__bf16)W[(k0 + j) * N + n];
    *(bf16x8*)(dst + (size_t)t * 8) = v;
}

// ---------------- node projection: nproj = node @ W_init + b ----------------
__global__ __launch_bounds__(256) void node_proj_mfma(
    const float* __restrict__ node_embed,   // [N,128]
    const __bf16* __restrict__ Wip,         // packed [4 nt][4 ks][64][8]
    const float* __restrict__ b_init,       // [64]
    __bf16* __restrict__ nproj,             // [N,64] bf16
    int n_nodes)
{
    __shared__ __bf16 nl[64 * 136];         // 17.4 KB, stride 136 (pad)
    const int tid = threadIdx.x;
    const int v0  = blockIdx.x * 64;

    {   // stage 64 node rows, fp32 -> bf16
        const int e = tid >> 2, q = tid & 3;
        const int v = v0 + e;
        if (v < n_nodes) {
            const float4* src = (const float4*)(node_embed + (size_t)v * 128 + q * 32);
            #pragma unroll
            for (int m = 0; m < 4; ++m) {
                float4 a = src[2 * m], b = src[2 * m + 1];
                bf16x8 w;
                w[0]=(__bf16)a.x; w[1]=(__bf16)a.y; w[2]=(__bf16)a.z; w[3]=(__bf16)a.w;
                w[4]=(__bf16)b.x; w[5]=(__bf16)b.y; w[6]=(__bf16)b.z; w[7]=(__bf16)b.w;
                *(bf16x8*)(nl + e * 136 + q * 32 + m * 8) = w;
            }
        } else {
            bf16x8 z = {};
            #pragma unroll
            for (int m = 0; m < 4; ++m)
                *(bf16x8*)(nl + e * 136 + q * 32 + m * 8) = z;
        }
    }
    __syncthreads();

    const int wav = tid >> 6, lane = tid & 63;
    const int l15 = lane & 15, quad = lane >> 4;

    f32x4 acc[4] = {};
    #pragma unroll
    for (int ks = 0; ks < 4; ++ks) {
        bf16x8 a = *(const bf16x8*)(nl + (16 * wav + l15) * 136 + ks * 32 + quad * 8);
        #pragma unroll
        for (int nt = 0; nt < 4; ++nt) {
            bf16x8 b = *(const bf16x8*)(Wip + ((size_t)(nt * 4 + ks) * 64 + lane) * 8);
            acc[nt] = __builtin_amdgcn_mfma_f32_16x16x32_bf16(a, b, acc[nt], 0, 0, 0);
        }
    }
    #pragma unroll
    for (int nt = 0; nt < 4; ++nt) {
        const float bb = b_init[nt * 16 + l15];
        #pragma unroll
        for (int r = 0; r < 4; ++r) {
            const int row = v0 + 16 * wav + quad * 4 + r;
            if (row < n_nodes)
                nproj[(size_t)row * 64 + nt * 16 + l15] = (__bf16)(acc[nt][r] + bb);
        }
    }
}

// ---------------- edge MLP ----------------
__global__ __launch_bounds__(256, 3) void edge_mlp_mfma(
    const float*  __restrict__ edge_embed,  // [E,64] fp32
    const int*    __restrict__ edge_index,  // [2,E]
    const __bf16* __restrict__ npr,         // [N,64] bf16
    const __bf16* __restrict__ W1p,         // [12 nt][6 ks][64][8]
    const float*  __restrict__ b1,
    const __bf16* __restrict__ W2p,
    const float*  __restrict__ b2,
    const __bf16* __restrict__ Wfp,         // [4 nt][6 ks][64][8]
    const float*  __restrict__ bfin,
    const float*  __restrict__ gamma,
    const float*  __restrict__ beta,
    float* __restrict__ out,                // [E,64]
    int n_edges)
{
    __shared__ __bf16 hl[64 * 200];         // h, then t2        (25.6 KB)
    __shared__ __bf16 tl[64 * 200];         // t1, then e overlay (25.6 KB)
    float* e_lds = reinterpret_cast<float*>(tl);   // after t1 dead: [64][68] fp32

    const int tid  = threadIdx.x;
    const int wav  = tid >> 6;
    const int lane = tid & 63;
    const int l15  = lane & 15, quad = lane >> 4;
    const int e0   = blockIdx.x * 64;

    // ---- staging: h[64][192] bf16 = [edge_embed | nproj[vi] | nproj[vj]] ----
    {
        const int e = tid >> 2, q = tid & 3;
        int eg = e0 + e;
        if (eg >= n_edges) eg = n_edges - 1;
        const int vi = edge_index[eg];
        const int vj = edge_index[n_edges + eg];
        // edge_embed 16 floats -> bf16
        const float4* s0 = (const float4*)(edge_embed + (size_t)eg * 64 + q * 16);
        #pragma unroll
        for (int m = 0; m < 2; ++m) {
            float4 a = s0[2 * m], b = s0[2 * m + 1];
            bf16x8 w;
            w[0]=(__bf16)a.x; w[1]=(__bf16)a.y; w[2]=(__bf16)a.z; w[3]=(__bf16)a.w;
            w[4]=(__bf16)b.x; w[5]=(__bf16)b.y; w[6]=(__bf16)b.z; w[7]=(__bf16)b.w;
            *(bf16x8*)(hl + e * 200 + q * 16 + m * 8) = w;
        }
        // nproj rows already bf16: raw 16B copies
        const int4* s1 = (const int4*)(npr + (size_t)vi * 64 + q * 16);
        const int4* s2 = (const int4*)(npr + (size_t)vj * 64 + q * 16);
        ((int4*)(hl + e * 200 + 64  + q * 16))[0] = s1[0];
        ((int4*)(hl + e * 200 + 64  + q * 16))[1] = s1[1];
        ((int4*)(hl + e * 200 + 128 + q * 16))[0] = s2[0];
        ((int4*)(hl + e * 200 + 128 + q * 16))[1] = s2[1];
    }
    __syncthreads();   // S0

    // ---- phase 1: acc = h@W1 (cols 48w..48w+48), racc = h@Wf (cols 16w..16w+16) ----
    f32x4 acc[3][4] = {};
    f32x4 racc[4]   = {};
    #pragma unroll 2
    for (int ks = 0; ks < 6; ++ks) {
        bf16x8 amt[4];
        #pragma unroll
        for (int mt = 0; mt < 4; ++mt)
            amt[mt] = *(const bf16x8*)(hl + (16 * mt + l15) * 200 + ks * 32 + quad * 8);
        #pragma unroll
        for (int nt = 0; nt < 3; ++nt) {
            bf16x8 b = *(const bf16x8*)(W1p + ((size_t)((3 * wav + nt) * 6 + ks) * 64 + lane) * 8);
            #pragma unroll
            for (int mt = 0; mt < 4; ++mt)
                acc[nt][mt] = __builtin_amdgcn_mfma_f32_16x16x32_bf16(amt[mt], b, acc[nt][mt], 0, 0, 0);
        }
        bf16x8 bw = *(const bf16x8*)(Wfp + ((size_t)(wav * 6 + ks) * 64 + lane) * 8);
        #pragma unroll
        for (int mt = 0; mt < 4; ++mt)
            racc[mt] = __builtin_amdgcn_mfma_f32_16x16x32_bf16(amt[mt], bw, racc[mt], 0, 0, 0);
    }
    // t1 = relu(acc + b1) -> tl
    #pragma unroll
    for (int nt = 0; nt < 3; ++nt) {
        const float bb = b1[48 * wav + nt * 16 + l15];
        #pragma unroll
        for (int mt = 0; mt < 4; ++mt)
            #pragma unroll
            for (int r = 0; r < 4; ++r)
                tl[(16 * mt + quad * 4 + r) * 200 + 48 * wav + nt * 16 + l15] =
                    (__bf16)fmaxf(acc[nt][mt][r] + bb, 0.0f);
    }
    __syncthreads();   // S1: t1 visible; all h reads of hl complete

    // ---- phase 2: acc = t1@W2; t2 -> hl (h dead) ----
    #pragma unroll
    for (int nt = 0; nt < 3; ++nt)
        #pragma unroll
        for (int mt = 0; mt < 4; ++mt)
            acc[nt][mt] = (f32x4){0.f, 0.f, 0.f, 0.f};
    #pragma unroll 2
    for (int ks = 0; ks < 6; ++ks) {
        bf16x8 amt[4];
        #pragma unroll
        for (int mt = 0; mt < 4; ++mt)
            amt[mt] = *(const bf16x8*)(tl + (16 * mt + l15) * 200 + ks * 32 + quad * 8);
        #pragma unroll
        for (int nt = 0; nt < 3; ++nt) {
            bf16x8 b = *(const bf16x8*)(W2p + ((size_t)((3 * wav + nt) * 6 + ks) * 64 + lane) * 8);
            #pragma unroll
            for (int mt = 0; mt < 4; ++mt)
                acc[nt][mt] = __builtin_amdgcn_mfma_f32_16x16x32_bf16(amt[mt], b, acc[nt][mt], 0, 0, 0);
        }
    }
    // t2 = relu(acc + b2) -> hl (no extra barrier needed: own-phase reads of
    // tl precede these writes in program order; hl's h is dead since S1)
    #pragma unroll
    for (int nt = 0; nt < 3; ++nt) {
        const float bb = b2[48 * wav + nt * 16 + l15];
        #pragma unroll
        for (int mt = 0; mt < 4; ++mt)
            #pragma unroll
            for (int r = 0; r < 4; ++r)
                hl[(16 * mt + quad * 4 + r) * 200 + 48 * wav + nt * 16 + l15] =
                    (__bf16)fmaxf(acc[nt][mt][r] + bb, 0.0f);
    }
    __syncthreads();   // S2: t2 visible; all t1 reads of tl complete

    // ---- phase 3: racc += t2@Wf (t2 in hl); e -> e_lds (tl region; t1 dead) ----
    #pragma unroll 2
    for (int ks = 0; ks < 6; ++ks) {
        bf16x8 bw = *(const bf16x8*)(Wfp + ((size_t)(wav * 6 + ks) * 64 + lane) * 8);
        #pragma unroll
        for (int mt = 0; mt < 4; ++mt) {
            bf16x8 a = *(const bf16x8*)(hl + (16 * mt + l15) * 200 + ks * 32 + quad * 8);
            racc[mt] = __builtin_amdgcn_mfma_f32_16x16x32_bf16(a, bw, racc[mt], 0, 0, 0);
        }
    }
    // E rows -> e_lds fp32 [64][68]  (tl region)
    {
        const float bb = bfin[16 * wav + l15];
        #pragma unroll
        for (int mt = 0; mt < 4; ++mt)
            #pragma unroll
            for (int r = 0; r < 4; ++r)
                e_lds[(16 * mt + quad * 4 + r) * 68 + 16 * wav + l15] = racc[mt][r] + bb;
    }
    __syncthreads();   // S3: e visible

    // ---- LayerNorm(64) + store ----
    {
        const int e = tid >> 2, q = tid & 3;
        const float* er = e_lds + e * 68 + q * 16;
        float vals[16];
        float s = 0.f, s2 = 0.f;
        #pragma unroll
        for (int i = 0; i < 16; ++i) {
            float v = er[i];
            vals[i] = v;
            s += v; s2 += v * v;
        }
        s  += __shfl_xor(s, 1);   s  += __shfl_xor(s, 2);
        s2 += __shfl_xor(s2, 1);  s2 += __shfl_xor(s2, 2);
        const float mu   = s * (1.0f / 64.0f);
        const float var  = s2 * (1.0f / 64.0f) - mu * mu;
        const float rstd = rsqrtf(var + LN_EPS);
        const int eg = e0 + e;
        if (eg < n_edges) {
            float* op = out + (size_t)eg * 64 + q * 16;
            #pragma unroll
            for (int i = 0; i < 16; ++i)
                op[i] = (vals[i] - mu) * rstd * gamma[q * 16 + i] + beta[q * 16 + i];
        }
    }
}

extern "C" void kernel_launch(void* const* d_in, const int* in_sizes, int n_in,
                              void* d_out, int out_size, void* d_ws, size_t ws_size,
                              hipStream_t stream) {
    const float* node_embed = (const float*)d_in[0];
    const float* edge_embed = (const float*)d_in[1];
    const int*   edge_index = (const int*)d_in[2];
    const float* W_init     = (const float*)d_in[3];
    const float* b_init     = (const float*)d_in[4];
    const float* W1         = (const float*)d_in[5];
    const float* b1         = (const float*)d_in[6];
    const float* W2         = (const float*)d_in[7];
    const float* b2         = (const float*)d_in[8];
    const float* Wf         = (const float*)d_in[9];
    const float* bfin       = (const float*)d_in[10];
    const float* gamma      = (const float*)d_in[11];
    const float* beta       = (const float*)d_in[12];
    float* out = (float*)d_out;

    const int n_nodes = in_sizes[0] / 128;
    const int n_edges = in_sizes[1] / 64;

    char* ws = (char*)d_ws;
    __bf16* nproj = (__bf16*)ws;
    __bf16* W1p   = (__bf16*)(ws + 12800000);
    __bf16* W2p   = (__bf16*)(ws + 12873728);
    __bf16* Wfp   = (__bf16*)(ws + 12947456);
    __bf16* Wip   = (__bf16*)(ws + 12972032);

    // pack weights (bf16 fragment layout)
    pack_weights_kernel<<<18, 256, 0, stream>>>(W1, 6, 12, 192, W1p, 12 * 6 * 64);
    pack_weights_kernel<<<18, 256, 0, stream>>>(W2, 6, 12, 192, W2p, 12 * 6 * 64);
    pack_weights_kernel<<< 6, 256, 0, stream>>>(Wf, 6,  4,  64, Wfp,  4 * 6 * 64);
    pack_weights_kernel<<< 4, 256, 0, stream>>>(W_init, 4, 4, 64, Wip, 4 * 4 * 64);

    node_proj_mfma<<<(n_nodes + 63) / 64, 256, 0, stream>>>(
        node_embed, Wip, b_init, nproj, n_nodes);

    edge_mlp_mfma<<<(n_edges + 63) / 64, 256, 0, stream>>>(
        edge_embed, edge_index, nproj,
        W1p, b1, W2p, b2, Wfp, bfin, gamma, beta, out, n_edges);
}

// Round 10
// 667.223 us; speedup vs baseline: 1.0070x; 1.0062x over previous
//
#include <hip/hip_runtime.h>

// EdgeTransition fused pipeline, bf16-MFMA version.
//
// FINAL (R10) = R4, the best verified passing kernel (671.4us, absmax 0.031).
//
// SESSION LEDGER (10 benches): R4 body passes; EVERY recompiled variant of
// edge_mlp_mfma fails with data-dependent absmax ~0.4-0.5 — including a
// semantics-preserving `#pragma unroll 2`->full-unroll change (R9), which is
// bit-equivalent math. Conclusion: a codegen-sensitive latent miscompile
// (suspected waitcnt/scheduling class, cf. hipcc lgkmcnt hazards) makes this
// kernel body un-editable in this toolchain; the ~3x latency headroom
// (MfmaUtil 25%, HBM 18.5%) is unreachable without recompiling the body.
// DO NOT perturb edge_mlp_mfma's code; it must match this source exactly.
//
// d_ws layout:
//   [0)            nproj bf16 [N_NODES, 64]              12,800,000 B
//   [+12800000)    W1p  packed bf16 frags (12 nt,6 ks)       73,728 B
//   [+12873728)    W2p  packed                               73,728 B
//   [+12947456)    Wfp  packed (4 nt, 6 ks)                  24,576 B
//   [+12972032)    Wip  packed (4 nt, 4 ks)                  16,384 B
//
// Fragment conventions (mfma_f32_16x16x32_bf16, guide §3 m89/m120-verified):
//   A: lane holds A[m=lane&15][k=quad*8+j], j=0..7   (quad = lane>>4)
//   B: lane holds B[k=quad*8+j][n=lane&15]
//   C/D: col = lane&15, row = quad*4 + reg

typedef __bf16 bf16x8 __attribute__((ext_vector_type(8)));
typedef float  f32x4  __attribute__((ext_vector_type(4)));

#define LN_EPS 1e-5f

// ---------------- weight packing ----------------
__global__ __launch_bounds__(256) void pack_weights_kernel(
    const float* __restrict__ W, int KS, int NT, int N,
    __bf16* __restrict__ dst, int total)
{
    const int t = blockIdx.x * 256 + threadIdx.x;
    if (t >= total) return;
    const int lane = t & 63;
    const int ks   = (t >> 6) % KS;
    const int nt   = t / (KS * 64);
    const int n  = nt * 16 + (lane & 15);
    const int k0 = ks * 32 + (lane >> 4) * 8;
    bf16x8 v;
    #pragma unroll
    for (int j = 0; j < 8; ++j) v[j] = (__bf16)W[(k0 + j) * N + n];
    *(bf16x8*)(dst + (size_t)t * 8) = v;
}

// ---------------- node projection: nproj = node @ W_init + b ----------------
__global__ __launch_bounds__(256) void node_proj_mfma(
    const float* __restrict__ node_embed,   // [N,128]
    const __bf16* __restrict__ Wip,         // packed [4 nt][4 ks][64][8]
    const float* __restrict__ b_init,       // [64]
    __bf16* __restrict__ nproj,             // [N,64] bf16
    int n_nodes)
{
    __shared__ __bf16 nl[64 * 136];         // 17.4 KB, stride 136 (pad)
    const int tid = threadIdx.x;
    const int v0  = blockIdx.x * 64;

    {   // stage 64 node rows, fp32 -> bf16
        const int e = tid >> 2, q = tid & 3;
        const int v = v0 + e;
        if (v < n_nodes) {
            const float4* src = (const float4*)(node_embed + (size_t)v * 128 + q * 32);
            #pragma unroll
            for (int m = 0; m < 4; ++m) {
                float4 a = src[2 * m], b = src[2 * m + 1];
                bf16x8 w;
                w[0]=(__bf16)a.x; w[1]=(__bf16)a.y; w[2]=(__bf16)a.z; w[3]=(__bf16)a.w;
                w[4]=(__bf16)b.x; w[5]=(__bf16)b.y; w[6]=(__bf16)b.z; w[7]=(__bf16)b.w;
                *(bf16x8*)(nl + e * 136 + q * 32 + m * 8) = w;
            }
        } else {
            bf16x8 z = {};
            #pragma unroll
            for (int m = 0; m < 4; ++m)
                *(bf16x8*)(nl + e * 136 + q * 32 + m * 8) = z;
        }
    }
    __syncthreads();

    const int wav = tid >> 6, lane = tid & 63;
    const int l15 = lane & 15, quad = lane >> 4;

    f32x4 acc[4] = {};
    #pragma unroll
    for (int ks = 0; ks < 4; ++ks) {
        bf16x8 a = *(const bf16x8*)(nl + (16 * wav + l15) * 136 + ks * 32 + quad * 8);
        #pragma unroll
        for (int nt = 0; nt < 4; ++nt) {
            bf16x8 b = *(const bf16x8*)(Wip + ((size_t)(nt * 4 + ks) * 64 + lane) * 8);
            acc[nt] = __builtin_amdgcn_mfma_f32_16x16x32_bf16(a, b, acc[nt], 0, 0, 0);
        }
    }
    #pragma unroll
    for (int nt = 0; nt < 4; ++nt) {
        const float bb = b_init[nt * 16 + l15];
        #pragma unroll
        for (int r = 0; r < 4; ++r) {
            const int row = v0 + 16 * wav + quad * 4 + r;
            if (row < n_nodes)
                nproj[(size_t)row * 64 + nt * 16 + l15] = (__bf16)(acc[nt][r] + bb);
        }
    }
}

// ---------------- edge MLP ----------------
__global__ __launch_bounds__(256, 3) void edge_mlp_mfma(
    const float*  __restrict__ edge_embed,  // [E,64] fp32
    const int*    __restrict__ edge_index,  // [2,E]
    const __bf16* __restrict__ npr,         // [N,64] bf16
    const __bf16* __restrict__ W1p,         // [12 nt][6 ks][64][8]
    const float*  __restrict__ b1,
    const __bf16* __restrict__ W2p,
    const float*  __restrict__ b2,
    const __bf16* __restrict__ Wfp,         // [4 nt][6 ks][64][8]
    const float*  __restrict__ bfin,
    const float*  __restrict__ gamma,
    const float*  __restrict__ beta,
    float* __restrict__ out,                // [E,64]
    int n_edges)
{
    __shared__ __bf16 hl[64 * 200];         // h, then t2        (25.6 KB)
    __shared__ __bf16 tl[64 * 200];         // t1, then e overlay (25.6 KB)
    float* e_lds = reinterpret_cast<float*>(tl);   // after t1 dead: [64][68] fp32

    const int tid  = threadIdx.x;
    const int wav  = tid >> 6;
    const int lane = tid & 63;
    const int l15  = lane & 15, quad = lane >> 4;
    const int e0   = blockIdx.x * 64;

    // ---- staging: h[64][192] bf16 = [edge_embed | nproj[vi] | nproj[vj]] ----
    {
        const int e = tid >> 2, q = tid & 3;
        int eg = e0 + e;
        if (eg >= n_edges) eg = n_edges - 1;
        const int vi = edge_index[eg];
        const int vj = edge_index[n_edges + eg];
        // edge_embed 16 floats -> bf16
        const float4* s0 = (const float4*)(edge_embed + (size_t)eg * 64 + q * 16);
        #pragma unroll
        for (int m = 0; m < 2; ++m) {
            float4 a = s0[2 * m], b = s0[2 * m + 1];
            bf16x8 w;
            w[0]=(__bf16)a.x; w[1]=(__bf16)a.y; w[2]=(__bf16)a.z; w[3]=(__bf16)a.w;
            w[4]=(__bf16)b.x; w[5]=(__bf16)b.y; w[6]=(__bf16)b.z; w[7]=(__bf16)b.w;
            *(bf16x8*)(hl + e * 200 + q * 16 + m * 8) = w;
        }
        // nproj rows already bf16: raw 16B copies
        const int4* s1 = (const int4*)(npr + (size_t)vi * 64 + q * 16);
        const int4* s2 = (const int4*)(npr + (size_t)vj * 64 + q * 16);
        ((int4*)(hl + e * 200 + 64  + q * 16))[0] = s1[0];
        ((int4*)(hl + e * 200 + 64  + q * 16))[1] = s1[1];
        ((int4*)(hl + e * 200 + 128 + q * 16))[0] = s2[0];
        ((int4*)(hl + e * 200 + 128 + q * 16))[1] = s2[1];
    }
    __syncthreads();   // S0

    // ---- phase 1: acc = h@W1 (cols 48w..48w+48), racc = h@Wf (cols 16w..16w+16) ----
    f32x4 acc[3][4] = {};
    f32x4 racc[4]   = {};
    #pragma unroll 2
    for (int ks = 0; ks < 6; ++ks) {
        bf16x8 amt[4];
        #pragma unroll
        for (int mt = 0; mt < 4; ++mt)
            amt[mt] = *(const bf16x8*)(hl + (16 * mt + l15) * 200 + ks * 32 + quad * 8);
        #pragma unroll
        for (int nt = 0; nt < 3; ++nt) {
            bf16x8 b = *(const bf16x8*)(W1p + ((size_t)((3 * wav + nt) * 6 + ks) * 64 + lane) * 8);
            #pragma unroll
            for (int mt = 0; mt < 4; ++mt)
                acc[nt][mt] = __builtin_amdgcn_mfma_f32_16x16x32_bf16(amt[mt], b, acc[nt][mt], 0, 0, 0);
        }
        bf16x8 bw = *(const bf16x8*)(Wfp + ((size_t)(wav * 6 + ks) * 64 + lane) * 8);
        #pragma unroll
        for (int mt = 0; mt < 4; ++mt)
            racc[mt] = __builtin_amdgcn_mfma_f32_16x16x32_bf16(amt[mt], bw, racc[mt], 0, 0, 0);
    }
    // t1 = relu(acc + b1) -> tl
    #pragma unroll
    for (int nt = 0; nt < 3; ++nt) {
        const float bb = b1[48 * wav + nt * 16 + l15];
        #pragma unroll
        for (int mt = 0; mt < 4; ++mt)
            #pragma unroll
            for (int r = 0; r < 4; ++r)
                tl[(16 * mt + quad * 4 + r) * 200 + 48 * wav + nt * 16 + l15] =
                    (__bf16)fmaxf(acc[nt][mt][r] + bb, 0.0f);
    }
    __syncthreads();   // S1: t1 visible; all h reads of hl complete

    // ---- phase 2: acc = t1@W2; t2 -> hl (h dead) ----
    #pragma unroll
    for (int nt = 0; nt < 3; ++nt)
        #pragma unroll
        for (int mt = 0; mt < 4; ++mt)
            acc[nt][mt] = (f32x4){0.f, 0.f, 0.f, 0.f};
    #pragma unroll 2
    for (int ks = 0; ks < 6; ++ks) {
        bf16x8 amt[4];
        #pragma unroll
        for (int mt = 0; mt < 4; ++mt)
            amt[mt] = *(const bf16x8*)(tl + (16 * mt + l15) * 200 + ks * 32 + quad * 8);
        #pragma unroll
        for (int nt = 0; nt < 3; ++nt) {
            bf16x8 b = *(const bf16x8*)(W2p + ((size_t)((3 * wav + nt) * 6 + ks) * 64 + lane) * 8);
            #pragma unroll
            for (int mt = 0; mt < 4; ++mt)
                acc[nt][mt] = __builtin_amdgcn_mfma_f32_16x16x32_bf16(amt[mt], b, acc[nt][mt], 0, 0, 0);
        }
    }
    // t2 = relu(acc + b2) -> hl (own-phase tl reads precede in program order;
    // hl's h is dead since S1)
    #pragma unroll
    for (int nt = 0; nt < 3; ++nt) {
        const float bb = b2[48 * wav + nt * 16 + l15];
        #pragma unroll
        for (int mt = 0; mt < 4; ++mt)
            #pragma unroll
            for (int r = 0; r < 4; ++r)
                hl[(16 * mt + quad * 4 + r) * 200 + 48 * wav + nt * 16 + l15] =
                    (__bf16)fmaxf(acc[nt][mt][r] + bb, 0.0f);
    }
    __syncthreads();   // S2: t2 visible; all t1 reads of tl complete

    // ---- phase 3: racc += t2@Wf (t2 in hl); e -> e_lds (tl region; t1 dead) ----
    #pragma unroll 2
    for (int ks = 0; ks < 6; ++ks) {
        bf16x8 bw = *(const bf16x8*)(Wfp + ((size_t)(wav * 6 + ks) * 64 + lane) * 8);
        #pragma unroll
        for (int mt = 0; mt < 4; ++mt) {
            bf16x8 a = *(const bf16x8*)(hl + (16 * mt + l15) * 200 + ks * 32 + quad * 8);
            racc[mt] = __builtin_amdgcn_mfma_f32_16x16x32_bf16(a, bw, racc[mt], 0, 0, 0);
        }
    }
    // E rows -> e_lds fp32 [64][68]  (tl region)
    {
        const float bb = bfin[16 * wav + l15];
        #pragma unroll
        for (int mt = 0; mt < 4; ++mt)
            #pragma unroll
            for (int r = 0; r < 4; ++r)
                e_lds[(16 * mt + quad * 4 + r) * 68 + 16 * wav + l15] = racc[mt][r] + bb;
    }
    __syncthreads();   // S3: e visible

    // ---- LayerNorm(64) + store ----
    {
        const int e = tid >> 2, q = tid & 3;
        const float* er = e_lds + e * 68 + q * 16;
        float vals[16];
        float s = 0.f, s2 = 0.f;
        #pragma unroll
        for (int i = 0; i < 16; ++i) {
            float v = er[i];
            vals[i] = v;
            s += v; s2 += v * v;
        }
        s  += __shfl_xor(s, 1);   s  += __shfl_xor(s, 2);
        s2 += __shfl_xor(s2, 1);  s2 += __shfl_xor(s2, 2);
        const float mu   = s * (1.0f / 64.0f);
        const float var  = s2 * (1.0f / 64.0f) - mu * mu;
        const float rstd = rsqrtf(var + LN_EPS);
        const int eg = e0 + e;
        if (eg < n_edges) {
            float* op = out + (size_t)eg * 64 + q * 16;
            #pragma unroll
            for (int i = 0; i < 16; ++i)
                op[i] = (vals[i] - mu) * rstd * gamma[q * 16 + i] + beta[q * 16 + i];
        }
    }
}

extern "C" void kernel_launch(void* const* d_in, const int* in_sizes, int n_in,
                              void* d_out, int out_size, void* d_ws, size_t ws_size,
                              hipStream_t stream) {
    const float* node_embed = (const float*)d_in[0];
    const float* edge_embed = (const float*)d_in[1];
    const int*   edge_index = (const int*)d_in[2];
    const float* W_init     = (const float*)d_in[3];
    const float* b_init     = (const float*)d_in[4];
    const float* W1         = (const float*)d_in[5];
    const float* b1         = (const float*)d_in[6];
    const float* W2         = (const float*)d_in[7];
    const float* b2         = (const float*)d_in[8];
    const float* Wf         = (const float*)d_in[9];
    const float* bfin       = (const float*)d_in[10];
    const float* gamma      = (const float*)d_in[11];
    const float* beta       = (const float*)d_in[12];
    float* out = (float*)d_out;

    const int n_nodes = in_sizes[0] / 128;
    const int n_edges = in_sizes[1] / 64;

    char* ws = (char*)d_ws;
    __bf16* nproj = (__bf16*)ws;
    __bf16* W1p   = (__bf16*)(ws + 12800000);
    __bf16* W2p   = (__bf16*)(ws + 12873728);
    __bf16* Wfp   = (__bf16*)(ws + 12947456);
    __bf16* Wip   = (__bf16*)(ws + 12972032);

    // pack weights (bf16 fragment layout)
    pack_weights_kernel<<<18, 256, 0, stream>>>(W1, 6, 12, 192, W1p, 12 * 6 * 64);
    pack_weights_kernel<<<18, 256, 0, stream>>>(W2, 6, 12, 192, W2p, 12 * 6 * 64);
    pack_weights_kernel<<< 6, 256, 0, stream>>>(Wf, 6,  4,  64, Wfp,  4 * 6 * 64);
    pack_weights_kernel<<< 4, 256, 0, stream>>>(W_init, 4, 4, 64, Wip, 4 * 4 * 64);

    node_proj_mfma<<<(n_nodes + 63) / 64, 256, 0, stream>>>(
        node_embed, Wip, b_init, nproj, n_nodes);

    edge_mlp_mfma<<<(n_edges + 63) / 64, 256, 0, stream>>>(
        edge_embed, edge_index, nproj,
        W1p, b1, W2p, b2, Wfp, bfin, gamma, beta, out, n_edges);
}

// Round 11
// 661.707 us; speedup vs baseline: 1.0154x; 1.0083x over previous
//
#include <hip/hip_runtime.h>

// EdgeTransition fused pipeline, bf16-MFMA version.
//
// R11 = R10 (verified 667.2us) with ONE change OUTSIDE the frozen kernel:
// the 4 pack_weights launches merged into 1 pack_all_weights launch
// (6 -> 3 total launches). edge_mlp_mfma and node_proj_mfma are
// BYTE-IDENTICAL to R10 — unchanged IR => unchanged ISA => the frozen
// body is not re-scheduled (all 7 failures required changed edge_mlp IR).
// Merged pack logic is verified-by-implication: it ran in R2/R3 where
// outputs were mostly-correct (absmax 0.4, not garbage) — broken weights
// would corrupt all outputs massively.
//
// SESSION LEDGER (11 benches): R4/R10 body passes; EVERY recompiled variant
// of edge_mlp_mfma fails with data-dependent absmax ~0.4-0.5 — including a
// semantics-preserving `#pragma unroll 2`->full-unroll change (R9, bit-
// equivalent math). Conclusion: codegen-sensitive latent miscompile class;
// DO NOT perturb edge_mlp_mfma's source; it must match this text exactly.
//
// d_ws layout:
//   [0)            nproj bf16 [N_NODES, 64]              12,800,000 B
//   [+12800000)    W1p  packed bf16 frags (12 nt,6 ks)       73,728 B
//   [+12873728)    W2p  packed                               73,728 B
//   [+12947456)    Wfp  packed (4 nt, 6 ks)                  24,576 B
//   [+12972032)    Wip  packed (4 nt, 4 ks)                  16,384 B
//
// Fragment conventions (mfma_f32_16x16x32_bf16, guide §3 m89/m120-verified):
//   A: lane holds A[m=lane&15][k=quad*8+j], j=0..7   (quad = lane>>4)
//   B: lane holds B[k=quad*8+j][n=lane&15]
//   C/D: col = lane&15, row = quad*4 + reg

typedef __bf16 bf16x8 __attribute__((ext_vector_type(8)));
typedef float  f32x4  __attribute__((ext_vector_type(4)));

#define LN_EPS 1e-5f

// ---------------- weight packing (all four weights, one launch) ----------------
// Fragment layout [nt][ks][lane][8]: lane holds B[k=ks*32+(lane>>4)*8+j][n=nt*16+(lane&15)]
__global__ __launch_bounds__(256) void pack_all_weights(
    const float* __restrict__ W1, const float* __restrict__ W2,
    const float* __restrict__ Wf, const float* __restrict__ Wi,
    __bf16* __restrict__ W1p, __bf16* __restrict__ W2p,
    __bf16* __restrict__ Wfp, __bf16* __restrict__ Wip)
{
    int t = blockIdx.x * 256 + threadIdx.x;
    const float* W; __bf16* dst; int KS, N;
    if (t < 4608)       { W = W1; dst = W1p; KS = 6; N = 192; }            // 12nt*6ks*64
    else if (t < 9216)  { W = W2; dst = W2p; KS = 6; N = 192; t -= 4608; } // 12nt*6ks*64
    else if (t < 10752) { W = Wf; dst = Wfp; KS = 6; N = 64;  t -= 9216; } // 4nt*6ks*64
    else if (t < 11776) { W = Wi; dst = Wip; KS = 4; N = 64;  t -= 10752; }// 4nt*4ks*64
    else return;
    const int lane = t & 63;
    const int ks   = (t >> 6) % KS;
    const int nt   = t / (KS * 64);
    const int n  = nt * 16 + (lane & 15);
    const int k0 = ks * 32 + (lane >> 4) * 8;
    bf16x8 v;
    #pragma unroll
    for (int j = 0; j < 8; ++j) v[j] = (__bf16)W[(k0 + j) * N + n];
    *(bf16x8*)(dst + (size_t)t * 8) = v;
}

// ---------------- node projection: nproj = node @ W_init + b ----------------
__global__ __launch_bounds__(256) void node_proj_mfma(
    const float* __restrict__ node_embed,   // [N,128]
    const __bf16* __restrict__ Wip,         // packed [4 nt][4 ks][64][8]
    const float* __restrict__ b_init,       // [64]
    __bf16* __restrict__ nproj,             // [N,64] bf16
    int n_nodes)
{
    __shared__ __bf16 nl[64 * 136];         // 17.4 KB, stride 136 (pad)
    const int tid = threadIdx.x;
    const int v0  = blockIdx.x * 64;

    {   // stage 64 node rows, fp32 -> bf16
        const int e = tid >> 2, q = tid & 3;
        const int v = v0 + e;
        if (v < n_nodes) {
            const float4* src = (const float4*)(node_embed + (size_t)v * 128 + q * 32);
            #pragma unroll
            for (int m = 0; m < 4; ++m) {
                float4 a = src[2 * m], b = src[2 * m + 1];
                bf16x8 w;
                w[0]=(__bf16)a.x; w[1]=(__bf16)a.y; w[2]=(__bf16)a.z; w[3]=(__bf16)a.w;
                w[4]=(__bf16)b.x; w[5]=(__bf16)b.y; w[6]=(__bf16)b.z; w[7]=(__bf16)b.w;
                *(bf16x8*)(nl + e * 136 + q * 32 + m * 8) = w;
            }
        } else {
            bf16x8 z = {};
            #pragma unroll
            for (int m = 0; m < 4; ++m)
                *(bf16x8*)(nl + e * 136 + q * 32 + m * 8) = z;
        }
    }
    __syncthreads();

    const int wav = tid >> 6, lane = tid & 63;
    const int l15 = lane & 15, quad = lane >> 4;

    f32x4 acc[4] = {};
    #pragma unroll
    for (int ks = 0; ks < 4; ++ks) {
        bf16x8 a = *(const bf16x8*)(nl + (16 * wav + l15) * 136 + ks * 32 + quad * 8);
        #pragma unroll
        for (int nt = 0; nt < 4; ++nt) {
            bf16x8 b = *(const bf16x8*)(Wip + ((size_t)(nt * 4 + ks) * 64 + lane) * 8);
            acc[nt] = __builtin_amdgcn_mfma_f32_16x16x32_bf16(a, b, acc[nt], 0, 0, 0);
        }
    }
    #pragma unroll
    for (int nt = 0; nt < 4; ++nt) {
        const float bb = b_init[nt * 16 + l15];
        #pragma unroll
        for (int r = 0; r < 4; ++r) {
            const int row = v0 + 16 * wav + quad * 4 + r;
            if (row < n_nodes)
                nproj[(size_t)row * 64 + nt * 16 + l15] = (__bf16)(acc[nt][r] + bb);
        }
    }
}

// ---------------- edge MLP ----------------
__global__ __launch_bounds__(256, 3) void edge_mlp_mfma(
    const float*  __restrict__ edge_embed,  // [E,64] fp32
    const int*    __restrict__ edge_index,  // [2,E]
    const __bf16* __restrict__ npr,         // [N,64] bf16
    const __bf16* __restrict__ W1p,         // [12 nt][6 ks][64][8]
    const float*  __restrict__ b1,
    const __bf16* __restrict__ W2p,
    const float*  __restrict__ b2,
    const __bf16* __restrict__ Wfp,         // [4 nt][6 ks][64][8]
    const float*  __restrict__ bfin,
    const float*  __restrict__ gamma,
    const float*  __restrict__ beta,
    float* __restrict__ out,                // [E,64]
    int n_edges)
{
    __shared__ __bf16 hl[64 * 200];         // h, then t2        (25.6 KB)
    __shared__ __bf16 tl[64 * 200];         // t1, then e overlay (25.6 KB)
    float* e_lds = reinterpret_cast<float*>(tl);   // after t1 dead: [64][68] fp32

    const int tid  = threadIdx.x;
    const int wav  = tid >> 6;
    const int lane = tid & 63;
    const int l15  = lane & 15, quad = lane >> 4;
    const int e0   = blockIdx.x * 64;

    // ---- staging: h[64][192] bf16 = [edge_embed | nproj[vi] | nproj[vj]] ----
    {
        const int e = tid >> 2, q = tid & 3;
        int eg = e0 + e;
        if (eg >= n_edges) eg = n_edges - 1;
        const int vi = edge_index[eg];
        const int vj = edge_index[n_edges + eg];
        // edge_embed 16 floats -> bf16
        const float4* s0 = (const float4*)(edge_embed + (size_t)eg * 64 + q * 16);
        #pragma unroll
        for (int m = 0; m < 2; ++m) {
            float4 a = s0[2 * m], b = s0[2 * m + 1];
            bf16x8 w;
            w[0]=(__bf16)a.x; w[1]=(__bf16)a.y; w[2]=(__bf16)a.z; w[3]=(__bf16)a.w;
            w[4]=(__bf16)b.x; w[5]=(__bf16)b.y; w[6]=(__bf16)b.z; w[7]=(__bf16)b.w;
            *(bf16x8*)(hl + e * 200 + q * 16 + m * 8) = w;
        }
        // nproj rows already bf16: raw 16B copies
        const int4* s1 = (const int4*)(npr + (size_t)vi * 64 + q * 16);
        const int4* s2 = (const int4*)(npr + (size_t)vj * 64 + q * 16);
        ((int4*)(hl + e * 200 + 64  + q * 16))[0] = s1[0];
        ((int4*)(hl + e * 200 + 64  + q * 16))[1] = s1[1];
        ((int4*)(hl + e * 200 + 128 + q * 16))[0] = s2[0];
        ((int4*)(hl + e * 200 + 128 + q * 16))[1] = s2[1];
    }
    __syncthreads();   // S0

    // ---- phase 1: acc = h@W1 (cols 48w..48w+48), racc = h@Wf (cols 16w..16w+16) ----
    f32x4 acc[3][4] = {};
    f32x4 racc[4]   = {};
    #pragma unroll 2
    for (int ks = 0; ks < 6; ++ks) {
        bf16x8 amt[4];
        #pragma unroll
        for (int mt = 0; mt < 4; ++mt)
            amt[mt] = *(const bf16x8*)(hl + (16 * mt + l15) * 200 + ks * 32 + quad * 8);
        #pragma unroll
        for (int nt = 0; nt < 3; ++nt) {
            bf16x8 b = *(const bf16x8*)(W1p + ((size_t)((3 * wav + nt) * 6 + ks) * 64 + lane) * 8);
            #pragma unroll
            for (int mt = 0; mt < 4; ++mt)
                acc[nt][mt] = __builtin_amdgcn_mfma_f32_16x16x32_bf16(amt[mt], b, acc[nt][mt], 0, 0, 0);
        }
        bf16x8 bw = *(const bf16x8*)(Wfp + ((size_t)(wav * 6 + ks) * 64 + lane) * 8);
        #pragma unroll
        for (int mt = 0; mt < 4; ++mt)
            racc[mt] = __builtin_amdgcn_mfma_f32_16x16x32_bf16(amt[mt], bw, racc[mt], 0, 0, 0);
    }
    // t1 = relu(acc + b1) -> tl
    #pragma unroll
    for (int nt = 0; nt < 3; ++nt) {
        const float bb = b1[48 * wav + nt * 16 + l15];
        #pragma unroll
        for (int mt = 0; mt < 4; ++mt)
            #pragma unroll
            for (int r = 0; r < 4; ++r)
                tl[(16 * mt + quad * 4 + r) * 200 + 48 * wav + nt * 16 + l15] =
                    (__bf16)fmaxf(acc[nt][mt][r] + bb, 0.0f);
    }
    __syncthreads();   // S1: t1 visible; all h reads of hl complete

    // ---- phase 2: acc = t1@W2; t2 -> hl (h dead) ----
    #pragma unroll
    for (int nt = 0; nt < 3; ++nt)
        #pragma unroll
        for (int mt = 0; mt < 4; ++mt)
            acc[nt][mt] = (f32x4){0.f, 0.f, 0.f, 0.f};
    #pragma unroll 2
    for (int ks = 0; ks < 6; ++ks) {
        bf16x8 amt[4];
        #pragma unroll
        for (int mt = 0; mt < 4; ++mt)
            amt[mt] = *(const bf16x8*)(tl + (16 * mt + l15) * 200 + ks * 32 + quad * 8);
        #pragma unroll
        for (int nt = 0; nt < 3; ++nt) {
            bf16x8 b = *(const bf16x8*)(W2p + ((size_t)((3 * wav + nt) * 6 + ks) * 64 + lane) * 8);
            #pragma unroll
            for (int mt = 0; mt < 4; ++mt)
                acc[nt][mt] = __builtin_amdgcn_mfma_f32_16x16x32_bf16(amt[mt], b, acc[nt][mt], 0, 0, 0);
        }
    }
    // t2 = relu(acc + b2) -> hl (own-phase tl reads precede in program order;
    // hl's h is dead since S1)
    #pragma unroll
    for (int nt = 0; nt < 3; ++nt) {
        const float bb = b2[48 * wav + nt * 16 + l15];
        #pragma unroll
        for (int mt = 0; mt < 4; ++mt)
            #pragma unroll
            for (int r = 0; r < 4; ++r)
                hl[(16 * mt + quad * 4 + r) * 200 + 48 * wav + nt * 16 + l15] =
                    (__bf16)fmaxf(acc[nt][mt][r] + bb, 0.0f);
    }
    __syncthreads();   // S2: t2 visible; all t1 reads of tl complete

    // ---- phase 3: racc += t2@Wf (t2 in hl); e -> e_lds (tl region; t1 dead) ----
    #pragma unroll 2
    for (int ks = 0; ks < 6; ++ks) {
        bf16x8 bw = *(const bf16x8*)(Wfp + ((size_t)(wav * 6 + ks) * 64 + lane) * 8);
        #pragma unroll
        for (int mt = 0; mt < 4; ++mt) {
            bf16x8 a = *(const bf16x8*)(hl + (16 * mt + l15) * 200 + ks * 32 + quad * 8);
            racc[mt] = __builtin_amdgcn_mfma_f32_16x16x32_bf16(a, bw, racc[mt], 0, 0, 0);
        }
    }
    // E rows -> e_lds fp32 [64][68]  (tl region)
    {
        const float bb = bfin[16 * wav + l15];
        #pragma unroll
        for (int mt = 0; mt < 4; ++mt)
            #pragma unroll
            for (int r = 0; r < 4; ++r)
                e_lds[(16 * mt + quad * 4 + r) * 68 + 16 * wav + l15] = racc[mt][r] + bb;
    }
    __syncthreads();   // S3: e visible

    // ---- LayerNorm(64) + store ----
    {
        const int e = tid >> 2, q = tid & 3;
        const float* er = e_lds + e * 68 + q * 16;
        float vals[16];
        float s = 0.f, s2 = 0.f;
        #pragma unroll
        for (int i = 0; i < 16; ++i) {
            float v = er[i];
            vals[i] = v;
            s += v; s2 += v * v;
        }
        s  += __shfl_xor(s, 1);   s  += __shfl_xor(s, 2);
        s2 += __shfl_xor(s2, 1);  s2 += __shfl_xor(s2, 2);
        const float mu   = s * (1.0f / 64.0f);
        const float var  = s2 * (1.0f / 64.0f) - mu * mu;
        const float rstd = rsqrtf(var + LN_EPS);
        const int eg = e0 + e;
        if (eg < n_edges) {
            float* op = out + (size_t)eg * 64 + q * 16;
            #pragma unroll
            for (int i = 0; i < 16; ++i)
                op[i] = (vals[i] - mu) * rstd * gamma[q * 16 + i] + beta[q * 16 + i];
        }
    }
}

extern "C" void kernel_launch(void* const* d_in, const int* in_sizes, int n_in,
                              void* d_out, int out_size, void* d_ws, size_t ws_size,
                              hipStream_t stream) {
    const float* node_embed = (const float*)d_in[0];
    const float* edge_embed = (const float*)d_in[1];
    const int*   edge_index = (const int*)d_in[2];
    const float* W_init     = (const float*)d_in[3];
    const float* b_init     = (const float*)d_in[4];
    const float* W1         = (const float*)d_in[5];
    const float* b1         = (const float*)d_in[6];
    const float* W2         = (const float*)d_in[7];
    const float* b2         = (const float*)d_in[8];
    const float* Wf         = (const float*)d_in[9];
    const float* bfin       = (const float*)d_in[10];
    const float* gamma      = (const float*)d_in[11];
    const float* beta       = (const float*)d_in[12];
    float* out = (float*)d_out;

    const int n_nodes = in_sizes[0] / 128;
    const int n_edges = in_sizes[1] / 64;

    char* ws = (char*)d_ws;
    __bf16* nproj = (__bf16*)ws;
    __bf16* W1p   = (__bf16*)(ws + 12800000);
    __bf16* W2p   = (__bf16*)(ws + 12873728);
    __bf16* Wfp   = (__bf16*)(ws + 12947456);
    __bf16* Wip   = (__bf16*)(ws + 12972032);

    // pack all weights (bf16 fragment layout), single launch
    pack_all_weights<<<46, 256, 0, stream>>>(W1, W2, Wf, W_init, W1p, W2p, Wfp, Wip);

    node_proj_mfma<<<(n_nodes + 63) / 64, 256, 0, stream>>>(
        node_embed, Wip, b_init, nproj, n_nodes);

    edge_mlp_mfma<<<(n_edges + 63) / 64, 256, 0, stream>>>(
        edge_embed, edge_index, nproj,
        W1p, b1, W2p, b2, Wfp, bfin, gamma, beta, out, n_edges);
}